// Round 1
// baseline (3207.768 us; speedup 1.0000x reference)
//
#include <hip/hip_runtime.h>
#include <math.h>

#define N_NODESC  262144
#define N_EDGESC  1048576
#define N_GRAPHSC 8192
#define NPG 32     // nodes per graph
#define EPG 128    // edges per graph
#define FXD 78
#define F2C 156
#define F3C 312
#define GHC 156    // Wg1 out
#define GOC 128    // Wg2 out
#define HS  36     // padded node-stride for transposed H tiles (16B-aligned float4 at r0%4==0)
#define RB  16     // rows per block in MLP kernels

// ---------------------------------------------------------------------------
// AH_t[k][r] = sum_c Hin_t[k][c] * A[r][c] ;  A stored transposed: As[c*HS + r]
template<int FIN>
__device__ __forceinline__ void a_mult(const float* __restrict__ Hin,
                                       float* __restrict__ AH,
                                       const float* __restrict__ As, int t) {
  const int r0 = (t & 7) * 4;
  for (int k = t >> 3; k < FIN; k += 32) {
    const float* hrow = Hin + k * HS;
    float ax = 0.f, ay = 0.f, az = 0.f, aw = 0.f;
#pragma unroll 8
    for (int c = 0; c < NPG; ++c) {
      float h = hrow[c];
      float4 a = *(const float4*)(As + c * HS + r0);
      ax = fmaf(h, a.x, ax); ay = fmaf(h, a.y, ay);
      az = fmaf(h, a.z, az); aw = fmaf(h, a.w, aw);
    }
    float4 o = {ax, ay, az, aw};
    *(float4*)(AH + k * HS + r0) = o;
  }
}

// Hout_t[f][n] = act( sum_k AH_t[k][n] * W[k][f] + b[f] )   (W row-major FIN x FOUT)
// POOL: instead of storing, relu + max over this thread's 4 nodes -> atomicMax into gmax
template<int FIN, int FOUT, int VEC, bool RELU, bool POOL>
__device__ __forceinline__ void mm_layer(const float* __restrict__ AH,
                                         const float* __restrict__ W,
                                         const float* __restrict__ bias,
                                         float* __restrict__ Hout,
                                         unsigned* __restrict__ gmax, int t) {
  const int n0 = (t & 7) * 4;
  constexpr int NF = FOUT / VEC;
  for (int fb = t >> 3; fb < NF; fb += 32) {
    const int f0 = fb * VEC;
    float acc[VEC][4];
#pragma unroll
    for (int v = 0; v < VEC; ++v) {
#pragma unroll
      for (int i = 0; i < 4; ++i) acc[v][i] = 0.f;
    }
#pragma unroll 4
    for (int k = 0; k < FIN; ++k) {
      float4 h = *(const float4*)(AH + k * HS + n0);
      const float* wp = W + (size_t)k * FOUT + f0;
      float wv[VEC];
      if constexpr (VEC == 4) {
        float4 w4 = *(const float4*)wp;
        wv[0] = w4.x; wv[1] = w4.y; wv[2] = w4.z; wv[3] = w4.w;
      } else {
        float2 w2 = *(const float2*)wp;
        wv[0] = w2.x; wv[1] = w2.y;
      }
#pragma unroll
      for (int v = 0; v < VEC; ++v) {
        acc[v][0] = fmaf(h.x, wv[v], acc[v][0]);
        acc[v][1] = fmaf(h.y, wv[v], acc[v][1]);
        acc[v][2] = fmaf(h.z, wv[v], acc[v][2]);
        acc[v][3] = fmaf(h.w, wv[v], acc[v][3]);
      }
    }
#pragma unroll
    for (int v = 0; v < VEC; ++v) {
      float bb = bias[f0 + v];
      float o0 = acc[v][0] + bb, o1 = acc[v][1] + bb;
      float o2 = acc[v][2] + bb, o3 = acc[v][3] + bb;
      if (RELU) {
        o0 = fmaxf(o0, 0.f); o1 = fmaxf(o1, 0.f);
        o2 = fmaxf(o2, 0.f); o3 = fmaxf(o3, 0.f);
      }
      if constexpr (POOL) {
        float m = fmaxf(fmaxf(o0, o1), fmaxf(o2, o3));
        atomicMax(&gmax[f0 + v], __float_as_uint(m));  // values >= 0 -> bit-monotone
      } else {
        float4 o = {o0, o1, o2, o3};
        *(float4*)(Hout + (f0 + v) * HS + n0) = o;
      }
    }
  }
}

// ---------------------------------------------------------------------------
// One block per graph, blockIdx.y selects drug. Whole GCN branch fused.
__global__ __launch_bounds__(256, 2)
void drug_kernel(const float* __restrict__ x1, const int* __restrict__ ei1,
                 const float* __restrict__ x2, const int* __restrict__ ei2,
                 const float* __restrict__ W1, const float* __restrict__ b1,
                 const float* __restrict__ W2, const float* __restrict__ b2,
                 const float* __restrict__ W3, const float* __restrict__ b3,
                 const float* __restrict__ Wg1, const float* __restrict__ bg1,
                 const float* __restrict__ Wg2, const float* __restrict__ bg2,
                 float* __restrict__ gout) {
  __shared__ __align__(16) float B0[F2C * HS];   // 156x36
  __shared__ __align__(16) float B1[F2C * HS];   // 156x36
  __shared__ __align__(16) float B2[FXD * HS];   // 78x36
  __shared__ __align__(16) float As[NPG * HS];   // A^T, As[c*HS+r] = A[r][c]
  __shared__ __align__(16) float gbuf[F3C];
  __shared__ __align__(16) float gg[GHC];
  __shared__ float deg[NPG];
  __shared__ float dinv[NPG];

  const int t = threadIdx.x;
  const int gid = blockIdx.x;
  const int drug = blockIdx.y;
  const float* __restrict__ x = drug ? x2 : x1;
  const int* __restrict__ ei = drug ? ei2 : ei1;
  const int nbase = gid * NPG;

  // ---- load x^T (32x78 -> B0[k][n]) ; 2496 contiguous floats
  const float* xg = x + (size_t)gid * (NPG * FXD);
  for (int i = t; i < (NPG * FXD) / 4; i += 256) {
    float4 v = ((const float4*)xg)[i];
    const float* vp = (const float*)&v;
    int idx = i * 4;
#pragma unroll
    for (int j = 0; j < 4; ++j) {
      int id2 = idx + j;
      int n = id2 / FXD;
      int k = id2 - n * FXD;
      B0[k * HS + n] = vp[j];
    }
  }

  // ---- degrees (src-count + self loop) and normalized adjacency
  if (t < NPG) deg[t] = 0.f;
  __syncthreads();
  if (t < EPG) {
    int s = ei[(size_t)gid * EPG + t] - nbase;
    atomicAdd(&deg[s], 1.0f);
  }
  __syncthreads();
  if (t < NPG) dinv[t] = 1.0f / sqrtf(deg[t] + 1.0f);
  for (int i = t; i < NPG * HS; i += 256) As[i] = 0.f;
  __syncthreads();
  if (t < EPG) {
    int s = ei[(size_t)gid * EPG + t] - nbase;
    int d = ei[(size_t)N_EDGESC + (size_t)gid * EPG + t] - nbase;
    atomicAdd(&As[d * HS + s], dinv[s] * dinv[d]);  // A[s][d] += (msg d->s)
  }
  if (t < NPG) atomicAdd(&As[t * HS + t], dinv[t] * dinv[t]);  // self loop
  __syncthreads();

  // ---- layer 1: x(78) -> h1(78)
  a_mult<FXD>(B0, B1, As, t);
  __syncthreads();
  mm_layer<FXD, FXD, 2, true, false>(B1, W1, b1, B2, nullptr, t);
  __syncthreads();
  // ---- layer 2: h1(78) -> h2(156)
  a_mult<FXD>(B2, B1, As, t);
  __syncthreads();
  mm_layer<FXD, F2C, 2, true, false>(B1, W2, b2, B0, nullptr, t);
  __syncthreads();
  // ---- layer 3: h2(156) -> relu -> max-pool(312), no H3 materialization
  a_mult<F2C>(B0, B1, As, t);
  for (int i = t; i < F3C; i += 256) ((unsigned*)gbuf)[i] = 0u;
  __syncthreads();
  mm_layer<F2C, F3C, 4, true, true>(B1, W3, b3, nullptr, (unsigned*)gbuf, t);
  __syncthreads();

  // ---- graph MLP: gg = relu(g @ Wg1 + bg1) ; out = gg @ Wg2 + bg2
  if (t < GHC) {
    float acc = 0.f;
#pragma unroll 2
    for (int k = 0; k < F3C; k += 4) {
      float4 gv = *(const float4*)(gbuf + k);
      acc = fmaf(gv.x, Wg1[(k + 0) * GHC + t], acc);
      acc = fmaf(gv.y, Wg1[(k + 1) * GHC + t], acc);
      acc = fmaf(gv.z, Wg1[(k + 2) * GHC + t], acc);
      acc = fmaf(gv.w, Wg1[(k + 3) * GHC + t], acc);
    }
    gg[t] = fmaxf(acc + bg1[t], 0.f);
  }
  __syncthreads();
  if (t < GOC) {
    float acc = 0.f;
#pragma unroll 2
    for (int k = 0; k < GHC; k += 4) {
      float4 gv = *(const float4*)(gg + k);
      acc = fmaf(gv.x, Wg2[(k + 0) * GOC + t], acc);
      acc = fmaf(gv.y, Wg2[(k + 1) * GOC + t], acc);
      acc = fmaf(gv.z, Wg2[(k + 2) * GOC + t], acc);
      acc = fmaf(gv.w, Wg2[(k + 3) * GOC + t], acc);
    }
    gout[((size_t)drug * N_GRAPHSC + gid) * GOC + t] = acc + bg2[t];
  }
}

// ---------------------------------------------------------------------------
// Cell MLP: relu(cell@Wr1+br1) -> relu(@Wr2+br2) -> @Wr3+br3 ; 16 rows/block
__global__ __launch_bounds__(256, 2)
void cell_kernel(const float* __restrict__ cell,
                 const float* __restrict__ Wr1, const float* __restrict__ br1,
                 const float* __restrict__ Wr2, const float* __restrict__ br2,
                 const float* __restrict__ Wr3, const float* __restrict__ br3,
                 float* __restrict__ cout) {
  __shared__ __align__(16) float ct[200 * RB];   // k-tile transposed
  __shared__ __align__(16) float h1[512 * RB];
  __shared__ __align__(16) float h2[256 * RB];
  const int t = threadIdx.x;
  const int R = blockIdx.x * RB;
  const int r0 = (t & 3) * 4;
  const int f = t >> 2;  // [0,64)

  float acc[4][8];
#pragma unroll
  for (int i = 0; i < 4; ++i)
#pragma unroll
    for (int j = 0; j < 8; ++j) acc[i][j] = 0.f;

  for (int k0 = 0; k0 < 1000; k0 += 200) {
    __syncthreads();
    for (int i = t; i < 200 * RB / 4; i += 256) {
      int r = i / 50, k4 = i - r * 50;
      float4 v = *(const float4*)(cell + (size_t)(R + r) * 1000 + k0 + k4 * 4);
      int kk = k4 * 4;
      ct[(kk + 0) * RB + r] = v.x; ct[(kk + 1) * RB + r] = v.y;
      ct[(kk + 2) * RB + r] = v.z; ct[(kk + 3) * RB + r] = v.w;
    }
    __syncthreads();
#pragma unroll 2
    for (int k = 0; k < 200; ++k) {
      float4 h = *(const float4*)(ct + k * RB + r0);
      const float* wr = Wr1 + (size_t)(k0 + k) * 512 + f;
#pragma unroll
      for (int j = 0; j < 8; ++j) {
        float w = wr[j * 64];
        acc[0][j] = fmaf(h.x, w, acc[0][j]);
        acc[1][j] = fmaf(h.y, w, acc[1][j]);
        acc[2][j] = fmaf(h.z, w, acc[2][j]);
        acc[3][j] = fmaf(h.w, w, acc[3][j]);
      }
    }
  }
  __syncthreads();
#pragma unroll
  for (int j = 0; j < 8; ++j) {
    int ff = f + j * 64;
    float bb = br1[ff];
    float4 o;
    o.x = fmaxf(acc[0][j] + bb, 0.f); o.y = fmaxf(acc[1][j] + bb, 0.f);
    o.z = fmaxf(acc[2][j] + bb, 0.f); o.w = fmaxf(acc[3][j] + bb, 0.f);
    *(float4*)(h1 + ff * RB + r0) = o;
  }
  __syncthreads();

  float a2[4][4];
#pragma unroll
  for (int i = 0; i < 4; ++i)
#pragma unroll
    for (int j = 0; j < 4; ++j) a2[i][j] = 0.f;
#pragma unroll 2
  for (int k = 0; k < 512; ++k) {
    float4 h = *(const float4*)(h1 + k * RB + r0);
    const float* wr = Wr2 + (size_t)k * 256 + f;
#pragma unroll
    for (int j = 0; j < 4; ++j) {
      float w = wr[j * 64];
      a2[0][j] = fmaf(h.x, w, a2[0][j]);
      a2[1][j] = fmaf(h.y, w, a2[1][j]);
      a2[2][j] = fmaf(h.z, w, a2[2][j]);
      a2[3][j] = fmaf(h.w, w, a2[3][j]);
    }
  }
#pragma unroll
  for (int j = 0; j < 4; ++j) {
    int ff = f + j * 64;
    float bb = br2[ff];
    float4 o;
    o.x = fmaxf(a2[0][j] + bb, 0.f); o.y = fmaxf(a2[1][j] + bb, 0.f);
    o.z = fmaxf(a2[2][j] + bb, 0.f); o.w = fmaxf(a2[3][j] + bb, 0.f);
    *(float4*)(h2 + ff * RB + r0) = o;
  }
  __syncthreads();

  float a3[4][2];
#pragma unroll
  for (int i = 0; i < 4; ++i) { a3[i][0] = 0.f; a3[i][1] = 0.f; }
#pragma unroll 4
  for (int k = 0; k < 256; ++k) {
    float4 h = *(const float4*)(h2 + k * RB + r0);
    const float* wr = Wr3 + (size_t)k * 128 + f;
#pragma unroll
    for (int j = 0; j < 2; ++j) {
      float w = wr[j * 64];
      a3[0][j] = fmaf(h.x, w, a3[0][j]);
      a3[1][j] = fmaf(h.y, w, a3[1][j]);
      a3[2][j] = fmaf(h.z, w, a3[2][j]);
      a3[3][j] = fmaf(h.w, w, a3[3][j]);
    }
  }
#pragma unroll
  for (int j = 0; j < 2; ++j) {
    int ff = f + j * 64;
    float bb = br3[ff];
#pragma unroll
    for (int i = 0; i < 4; ++i)
      cout[(size_t)(R + r0 + i) * GOC + ff] = a3[i][j] + bb;  // no relu on layer 3
  }
}

// ---------------------------------------------------------------------------
// Head: concat [g1,g2,c] -> L2 normalize (folded into epilogue as row scale)
// -> prelu(@Wf1+bf1) -> prelu(@Wf2+bf2) -> sigmoid(@Wo+bo)
__global__ __launch_bounds__(256, 2)
void head_kernel(const float* __restrict__ g1, const float* __restrict__ g2,
                 const float* __restrict__ cc,
                 const float* __restrict__ Wf1, const float* __restrict__ bf1,
                 const float* __restrict__ Wf2, const float* __restrict__ bf2,
                 const float* __restrict__ Wo, const float* __restrict__ bo,
                 const float* __restrict__ pa, float* __restrict__ out) {
  __shared__ __align__(16) float xct[384 * RB];
  __shared__ __align__(16) float h1[512 * RB];
  __shared__ float ssq[RB];
  __shared__ float scal[RB];
  __shared__ float red[256];
  float* h2 = xct;  // alias: xct dead after L1 k-loop; barriers make this safe

  const int t = threadIdx.x;
  const int R = blockIdx.x * RB;
  if (t < RB) ssq[t] = 0.f;
  __syncthreads();
  for (int i = t; i < 384 * RB / 4; i += 256) {
    int r = i / 96, q = i - r * 96;
    int col = q * 4;
    const float* src;
    int c2;
    if (col < 128)      { src = g1; c2 = col; }
    else if (col < 256) { src = g2; c2 = col - 128; }
    else                { src = cc; c2 = col - 256; }
    float4 v = *(const float4*)(src + (size_t)(R + r) * GOC + c2);
    xct[(col + 0) * RB + r] = v.x; xct[(col + 1) * RB + r] = v.y;
    xct[(col + 2) * RB + r] = v.z; xct[(col + 3) * RB + r] = v.w;
    atomicAdd(&ssq[r], v.x * v.x + v.y * v.y + v.z * v.z + v.w * v.w);
  }
  __syncthreads();
  if (t < RB) scal[t] = 1.0f / fmaxf(sqrtf(ssq[t]), 1e-12f);
  __syncthreads();

  const float a = pa[0];
  const int r0 = (t & 3) * 4;
  const int f = t >> 2;

  float acc[4][8];
#pragma unroll
  for (int i = 0; i < 4; ++i)
#pragma unroll
    for (int j = 0; j < 8; ++j) acc[i][j] = 0.f;
#pragma unroll 2
  for (int k = 0; k < 384; ++k) {
    float4 h = *(const float4*)(xct + k * RB + r0);
    const float* wr = Wf1 + (size_t)k * 512 + f;
#pragma unroll
    for (int j = 0; j < 8; ++j) {
      float w = wr[j * 64];
      acc[0][j] = fmaf(h.x, w, acc[0][j]);
      acc[1][j] = fmaf(h.y, w, acc[1][j]);
      acc[2][j] = fmaf(h.z, w, acc[2][j]);
      acc[3][j] = fmaf(h.w, w, acc[3][j]);
    }
  }
  __syncthreads();  // all xct reads done before h1 write (and later h2 alias write)
#pragma unroll
  for (int j = 0; j < 8; ++j) {
    int ff = f + j * 64;
    float bb = bf1[ff];
    float4 o;
    float v0 = acc[0][j] * scal[r0 + 0] + bb; o.x = v0 >= 0.f ? v0 : a * v0;
    float v1 = acc[1][j] * scal[r0 + 1] + bb; o.y = v1 >= 0.f ? v1 : a * v1;
    float v2 = acc[2][j] * scal[r0 + 2] + bb; o.z = v2 >= 0.f ? v2 : a * v2;
    float v3 = acc[3][j] * scal[r0 + 3] + bb; o.w = v3 >= 0.f ? v3 : a * v3;
    *(float4*)(h1 + ff * RB + r0) = o;
  }
  __syncthreads();

  float a2[4][2];
#pragma unroll
  for (int i = 0; i < 4; ++i) { a2[i][0] = 0.f; a2[i][1] = 0.f; }
#pragma unroll 2
  for (int k = 0; k < 512; ++k) {
    float4 h = *(const float4*)(h1 + k * RB + r0);
    const float* wr = Wf2 + (size_t)k * 128 + f;
#pragma unroll
    for (int j = 0; j < 2; ++j) {
      float w = wr[j * 64];
      a2[0][j] = fmaf(h.x, w, a2[0][j]);
      a2[1][j] = fmaf(h.y, w, a2[1][j]);
      a2[2][j] = fmaf(h.z, w, a2[2][j]);
      a2[3][j] = fmaf(h.w, w, a2[3][j]);
    }
  }
  __syncthreads();  // h1 reads done; h2 aliases xct (already safe), keep barrier before writes
#pragma unroll
  for (int j = 0; j < 2; ++j) {
    int ff = f + j * 64;
    float bb = bf2[ff];
#pragma unroll
    for (int i = 0; i < 4; ++i) {
      float v = a2[i][j] + bb;
      v = v >= 0.f ? v : a * v;
      h2[ff * RB + (r0 + i)] = v;
    }
  }
  __syncthreads();

  {
    int r = t >> 4, kp = t & 15;
    float p = 0.f;
#pragma unroll
    for (int jj = 0; jj < 8; ++jj) {
      int k = kp + 16 * jj;
      p = fmaf(h2[k * RB + r], Wo[k], p);
    }
    red[t] = p;
  }
  __syncthreads();
  if (t < RB) {
    float s = bo[0];
#pragma unroll
    for (int i = 0; i < 16; ++i) s += red[t * 16 + i];
    out[R + t] = 1.0f / (1.0f + expf(-s));
  }
}

// ---------------------------------------------------------------------------
extern "C" void kernel_launch(void* const* d_in, const int* in_sizes, int n_in,
                              void* d_out, int out_size, void* d_ws, size_t ws_size,
                              hipStream_t stream) {
  const float* x1  = (const float*)d_in[0];
  const int*   ei1 = (const int*)d_in[1];
  const float* x2  = (const float*)d_in[2];
  const int*   ei2 = (const int*)d_in[3];
  const float* cel = (const float*)d_in[4];
  const float* W1  = (const float*)d_in[7];
  const float* b1  = (const float*)d_in[8];
  const float* W2  = (const float*)d_in[9];
  const float* b2  = (const float*)d_in[10];
  const float* W3  = (const float*)d_in[11];
  const float* b3  = (const float*)d_in[12];
  const float* Wg1 = (const float*)d_in[13];
  const float* bg1 = (const float*)d_in[14];
  const float* Wg2 = (const float*)d_in[15];
  const float* bg2 = (const float*)d_in[16];
  const float* Wr1 = (const float*)d_in[17];
  const float* br1 = (const float*)d_in[18];
  const float* Wr2 = (const float*)d_in[19];
  const float* br2 = (const float*)d_in[20];
  const float* Wr3 = (const float*)d_in[21];
  const float* br3 = (const float*)d_in[22];
  const float* Wf1 = (const float*)d_in[23];
  const float* bf1 = (const float*)d_in[24];
  const float* Wf2 = (const float*)d_in[25];
  const float* bf2 = (const float*)d_in[26];
  const float* Wo  = (const float*)d_in[27];
  const float* bo  = (const float*)d_in[28];
  const float* pa  = (const float*)d_in[29];

  float* ws    = (float*)d_ws;
  float* g1buf = ws;                                   // 8192*128
  float* g2buf = ws + (size_t)N_GRAPHSC * GOC;         // 8192*128
  float* cbuf  = ws + (size_t)2 * N_GRAPHSC * GOC;     // 8192*128
  float* outp  = (float*)d_out;

  dim3 dgrid(N_GRAPHSC, 2);
  drug_kernel<<<dgrid, dim3(256), 0, stream>>>(
      x1, ei1, x2, ei2, W1, b1, W2, b2, W3, b3, Wg1, bg1, Wg2, bg2, g1buf);
  cell_kernel<<<dim3(512), dim3(256), 0, stream>>>(
      cel, Wr1, br1, Wr2, br2, Wr3, br3, cbuf);
  head_kernel<<<dim3(512), dim3(256), 0, stream>>>(
      g1buf, g2buf, cbuf, Wf1, bf1, Wf2, bf2, Wo, bo, pa, outp);
}

// Round 2
// 2864.829 us; speedup vs baseline: 1.1197x; 1.1197x over previous
//
#include <hip/hip_runtime.h>
#include <math.h>

#define N_EDGESC  1048576
#define N_GRAPHSC 8192
#define NPG 32     // nodes per graph
#define EPG 128    // edges per graph
#define FXD 78
#define F2C 156
#define F3C 312
#define GHC 156    // Wg1 out
#define GOC 128    // Wg2 out
#define HS  36     // padded node-stride: bank (4k+r0)%32 distinct across 8 k-groups
#define RBC 8      // rows per block in MLP kernels

// ---------------------------------------------------------------------------
// IN-PLACE A-aggregation: H[k][r] <- sum_c H[k][c] * A[r][c]  (A^T in As)
// Row k is read AND written only by its own 8-lane group -> no cross-group
// hazard; within the group all reads (dataflow) precede the single store.
template<int FIN>
__device__ __forceinline__ void a_mult_ip(float* __restrict__ H,
                                          const float* __restrict__ As, int t) {
  const int r0 = (t & 7) * 4;
  for (int k = t >> 3; k < FIN; k += 32) {
    float* hrow = H + k * HS;
    float ax = 0.f, ay = 0.f, az = 0.f, aw = 0.f;
#pragma unroll
    for (int c = 0; c < NPG; c += 4) {
      float4 h4 = *(const float4*)(hrow + c);
      float4 a0 = *(const float4*)(As + (c + 0) * HS + r0);
      float4 a1 = *(const float4*)(As + (c + 1) * HS + r0);
      float4 a2 = *(const float4*)(As + (c + 2) * HS + r0);
      float4 a3 = *(const float4*)(As + (c + 3) * HS + r0);
      ax = fmaf(h4.x, a0.x, ax); ay = fmaf(h4.x, a0.y, ay);
      az = fmaf(h4.x, a0.z, az); aw = fmaf(h4.x, a0.w, aw);
      ax = fmaf(h4.y, a1.x, ax); ay = fmaf(h4.y, a1.y, ay);
      az = fmaf(h4.y, a1.z, az); aw = fmaf(h4.y, a1.w, aw);
      ax = fmaf(h4.z, a2.x, ax); ay = fmaf(h4.z, a2.y, ay);
      az = fmaf(h4.z, a2.z, az); aw = fmaf(h4.z, a2.w, aw);
      ax = fmaf(h4.w, a3.x, ax); ay = fmaf(h4.w, a3.y, ay);
      az = fmaf(h4.w, a3.z, az); aw = fmaf(h4.w, a3.w, aw);
    }
    float4 o = {ax, ay, az, aw};
    *(float4*)(hrow + r0) = o;
  }
}

// Hout[f][n] = act( sum_k AH[k][n] * W[k][f] + b[f] )  (W row-major FIN x FOUT)
// POOL: relu + max over this thread's 4 nodes -> atomicMax into gmax
template<int FIN, int FOUT, int VEC, bool RELU, bool POOL>
__device__ __forceinline__ void mm_layer(const float* __restrict__ AH,
                                         const float* __restrict__ W,
                                         const float* __restrict__ bias,
                                         float* __restrict__ Hout,
                                         unsigned* __restrict__ gmax, int t) {
  const int n0 = (t & 7) * 4;
  constexpr int NF = FOUT / VEC;
  for (int fb = t >> 3; fb < NF; fb += 32) {
    const int f0 = fb * VEC;
    float acc[VEC][4];
#pragma unroll
    for (int v = 0; v < VEC; ++v) {
#pragma unroll
      for (int i = 0; i < 4; ++i) acc[v][i] = 0.f;
    }
#pragma unroll 4
    for (int k = 0; k < FIN; ++k) {
      float4 h = *(const float4*)(AH + k * HS + n0);
      const float* wp = W + (size_t)k * FOUT + f0;
      float wv[VEC];
      if constexpr (VEC == 4) {
        float4 w4 = *(const float4*)wp;
        wv[0] = w4.x; wv[1] = w4.y; wv[2] = w4.z; wv[3] = w4.w;
      } else {
        float2 w2 = *(const float2*)wp;
        wv[0] = w2.x; wv[1] = w2.y;
      }
#pragma unroll
      for (int v = 0; v < VEC; ++v) {
        acc[v][0] = fmaf(h.x, wv[v], acc[v][0]);
        acc[v][1] = fmaf(h.y, wv[v], acc[v][1]);
        acc[v][2] = fmaf(h.z, wv[v], acc[v][2]);
        acc[v][3] = fmaf(h.w, wv[v], acc[v][3]);
      }
    }
#pragma unroll
    for (int v = 0; v < VEC; ++v) {
      float bb = bias[f0 + v];
      float o0 = acc[v][0] + bb, o1 = acc[v][1] + bb;
      float o2 = acc[v][2] + bb, o3 = acc[v][3] + bb;
      if (RELU) {
        o0 = fmaxf(o0, 0.f); o1 = fmaxf(o1, 0.f);
        o2 = fmaxf(o2, 0.f); o3 = fmaxf(o3, 0.f);
      }
      if constexpr (POOL) {
        float m = fmaxf(fmaxf(o0, o1), fmaxf(o2, o3));
        atomicMax(&gmax[f0 + v], __float_as_uint(m));  // relu'd >= 0 -> monotone
      } else {
        float4 o = {o0, o1, o2, o3};
        *(float4*)(Hout + (f0 + v) * HS + n0) = o;
      }
    }
  }
}

// ---------------------------------------------------------------------------
// One block per graph, blockIdx.y = drug. LDS 38304 B -> 4 blocks/CU.
__global__ __launch_bounds__(256, 4)
void drug_kernel(const float* __restrict__ x1, const int* __restrict__ ei1,
                 const float* __restrict__ x2, const int* __restrict__ ei2,
                 const float* __restrict__ W1, const float* __restrict__ b1,
                 const float* __restrict__ W2, const float* __restrict__ b2,
                 const float* __restrict__ W3, const float* __restrict__ b3,
                 const float* __restrict__ Wg1, const float* __restrict__ bg1,
                 const float* __restrict__ Wg2, const float* __restrict__ bg2,
                 float* __restrict__ gout) {
  __shared__ __align__(16) float X[F2C * HS];   // 156x36 = 22464 B
  __shared__ __align__(16) float Y[FXD * HS];   // 78x36  = 11232 B
  __shared__ __align__(16) float As[NPG * HS];  //          4608 B
  // aliases into Y (lifetimes disjoint):
  float* deg = Y;                 // [0..31]   alive only until As built
  float* gbuf = Y;                // [0..311]  alive after Y(h-AH2) dead
  unsigned* gbufU = (unsigned*)Y;
  float* gg = Y + 512;            // [512..667]

  const int t = threadIdx.x;
  const int gid = blockIdx.x;
  const int drug = blockIdx.y;
  const float* __restrict__ x = drug ? x2 : x1;
  const int* __restrict__ ei = drug ? ei2 : ei1;
  const int nbase = gid * NPG;

  // ---- P0: zero deg + As, load x^T -> X
  if (t < NPG) deg[t] = 0.f;
  for (int i = t; i < NPG * HS; i += 256) As[i] = 0.f;
  const float* xg = x + (size_t)gid * (NPG * FXD);
  for (int i = t; i < (NPG * FXD) / 4; i += 256) {
    float4 v = ((const float4*)xg)[i];
    const float* vp = (const float*)&v;
    int idx = i * 4;
#pragma unroll
    for (int j = 0; j < 4; ++j) {
      int id2 = idx + j;
      int n = id2 / FXD;
      int k = id2 - n * FXD;
      X[k * HS + n] = vp[j];
    }
  }
  int s = 0, d = 0;
  if (t < EPG) {
    s = ei[(size_t)gid * EPG + t] - nbase;
    d = ei[(size_t)N_EDGESC + (size_t)gid * EPG + t] - nbase;
  }
  __syncthreads();
  // ---- P1: degree count
  if (t < EPG) atomicAdd(&deg[s], 1.0f);
  __syncthreads();
  // ---- P2: normalized adjacency (dinv computed on the fly)
  if (t < EPG) {
    float w = rsqrtf(deg[s] + 1.0f) * rsqrtf(deg[d] + 1.0f);
    atomicAdd(&As[d * HS + s], w);   // A[s][d]: msg d->s
  }
  if (t < NPG) atomicAdd(&As[t * HS + t], 1.0f / (deg[t] + 1.0f));
  __syncthreads();

  // ---- layer 1
  a_mult_ip<FXD>(X, As, t);
  __syncthreads();
  mm_layer<FXD, FXD, 2, true, false>(X, W1, b1, Y, nullptr, t);  // deg dead now
  __syncthreads();
  // ---- layer 2
  a_mult_ip<FXD>(Y, As, t);
  __syncthreads();
  mm_layer<FXD, F2C, 2, true, false>(Y, W2, b2, X, nullptr, t);
  __syncthreads();
  // ---- layer 3 + pool (Y dead: gbuf lives there)
  a_mult_ip<F2C>(X, As, t);
  for (int i = t; i < F3C; i += 256) gbufU[i] = 0u;
  __syncthreads();
  mm_layer<F2C, F3C, 4, true, true>(X, W3, b3, nullptr, gbufU, t);
  __syncthreads();

  // ---- graph MLP
  if (t < GHC) {
    float acc = 0.f;
#pragma unroll 2
    for (int k = 0; k < F3C; k += 4) {
      float4 gv = *(const float4*)(gbuf + k);
      acc = fmaf(gv.x, Wg1[(k + 0) * GHC + t], acc);
      acc = fmaf(gv.y, Wg1[(k + 1) * GHC + t], acc);
      acc = fmaf(gv.z, Wg1[(k + 2) * GHC + t], acc);
      acc = fmaf(gv.w, Wg1[(k + 3) * GHC + t], acc);
    }
    gg[t] = fmaxf(acc + bg1[t], 0.f);
  }
  __syncthreads();
  if (t < GOC) {
    float acc = 0.f;
#pragma unroll 2
    for (int k = 0; k < GHC; k += 4) {
      float4 gv = *(const float4*)(gg + k);
      acc = fmaf(gv.x, Wg2[(k + 0) * GOC + t], acc);
      acc = fmaf(gv.y, Wg2[(k + 1) * GOC + t], acc);
      acc = fmaf(gv.z, Wg2[(k + 2) * GOC + t], acc);
      acc = fmaf(gv.w, Wg2[(k + 3) * GOC + t], acc);
    }
    gout[((size_t)drug * N_GRAPHSC + gid) * GOC + t] = acc + bg2[t];
  }
}

// ---------------------------------------------------------------------------
// Cell MLP, RB=8 -> 1024 blocks, LDS 24.6 KB -> 4 blocks/CU resident.
// U holds ct (stage1) then h1 (stage2); h2 separate.
__global__ __launch_bounds__(256, 4)
void cell_kernel(const float* __restrict__ cell,
                 const float* __restrict__ Wr1, const float* __restrict__ br1,
                 const float* __restrict__ Wr2, const float* __restrict__ br2,
                 const float* __restrict__ Wr3, const float* __restrict__ br3,
                 float* __restrict__ cout) {
  __shared__ __align__(16) float U[512 * RBC];   // 16384 B
  __shared__ __align__(16) float h2[256 * RBC];  //  8192 B
  const int t = threadIdx.x;
  const int R = blockIdx.x * RBC;
  const int r0 = (t & 1) * 4;
  const int f = t >> 1;  // [0,128)

  float acc[4][4];
#pragma unroll
  for (int i = 0; i < 4; ++i)
#pragma unroll
    for (int j = 0; j < 4; ++j) acc[i][j] = 0.f;

  for (int k0 = 0; k0 < 1000; k0 += 200) {
    __syncthreads();
    for (int i = t; i < 400; i += 256) {       // 8 rows x 50 float4
      int r = i / 50, k4 = i - r * 50;
      float4 v = *(const float4*)(cell + (size_t)(R + r) * 1000 + k0 + k4 * 4);
      int kk = k4 * 4;
      U[(kk + 0) * RBC + r] = v.x; U[(kk + 1) * RBC + r] = v.y;
      U[(kk + 2) * RBC + r] = v.z; U[(kk + 3) * RBC + r] = v.w;
    }
    __syncthreads();
#pragma unroll 2
    for (int k = 0; k < 200; ++k) {
      float4 h = *(const float4*)(U + k * RBC + r0);
      const float* wr = Wr1 + (size_t)(k0 + k) * 512 + f;
#pragma unroll
      for (int j = 0; j < 4; ++j) {
        float w = wr[j * 128];
        acc[0][j] = fmaf(h.x, w, acc[0][j]);
        acc[1][j] = fmaf(h.y, w, acc[1][j]);
        acc[2][j] = fmaf(h.z, w, acc[2][j]);
        acc[3][j] = fmaf(h.w, w, acc[3][j]);
      }
    }
  }
  __syncthreads();   // ct region dead -> U becomes h1
#pragma unroll
  for (int j = 0; j < 4; ++j) {
    int ff = f + j * 128;
    float bb = br1[ff];
    float4 o;
    o.x = fmaxf(acc[0][j] + bb, 0.f); o.y = fmaxf(acc[1][j] + bb, 0.f);
    o.z = fmaxf(acc[2][j] + bb, 0.f); o.w = fmaxf(acc[3][j] + bb, 0.f);
    *(float4*)(U + ff * RBC + r0) = o;
  }
  __syncthreads();

  float a2[4][2];
#pragma unroll
  for (int i = 0; i < 4; ++i) { a2[i][0] = 0.f; a2[i][1] = 0.f; }
#pragma unroll 2
  for (int k = 0; k < 512; ++k) {
    float4 h = *(const float4*)(U + k * RBC + r0);
    const float* wr = Wr2 + (size_t)k * 256 + f;
#pragma unroll
    for (int j = 0; j < 2; ++j) {
      float w = wr[j * 128];
      a2[0][j] = fmaf(h.x, w, a2[0][j]);
      a2[1][j] = fmaf(h.y, w, a2[1][j]);
      a2[2][j] = fmaf(h.z, w, a2[2][j]);
      a2[3][j] = fmaf(h.w, w, a2[3][j]);
    }
  }
#pragma unroll
  for (int j = 0; j < 2; ++j) {  // h2 disjoint from U: no barrier needed
    int ff = f + j * 128;
    float bb = br2[ff];
    float4 o;
    o.x = fmaxf(a2[0][j] + bb, 0.f); o.y = fmaxf(a2[1][j] + bb, 0.f);
    o.z = fmaxf(a2[2][j] + bb, 0.f); o.w = fmaxf(a2[3][j] + bb, 0.f);
    *(float4*)(h2 + ff * RBC + r0) = o;
  }
  __syncthreads();

  float a3[4] = {0.f, 0.f, 0.f, 0.f};
#pragma unroll 4
  for (int k = 0; k < 256; ++k) {
    float4 h = *(const float4*)(h2 + k * RBC + r0);
    float w = Wr3[(size_t)k * 128 + f];
    a3[0] = fmaf(h.x, w, a3[0]); a3[1] = fmaf(h.y, w, a3[1]);
    a3[2] = fmaf(h.z, w, a3[2]); a3[3] = fmaf(h.w, w, a3[3]);
  }
  float bb = br3[f];
#pragma unroll
  for (int i = 0; i < 4; ++i)
    cout[(size_t)(R + r0 + i) * GOC + f] = a3[i] + bb;  // no relu
}

// ---------------------------------------------------------------------------
// Head, RB=8 -> 1024 blocks. U holds xct then h1; h2 separate. ~21.7 KB.
__global__ __launch_bounds__(256, 4)
void head_kernel(const float* __restrict__ g1, const float* __restrict__ g2,
                 const float* __restrict__ cc,
                 const float* __restrict__ Wf1, const float* __restrict__ bf1,
                 const float* __restrict__ Wf2, const float* __restrict__ bf2,
                 const float* __restrict__ Wo, const float* __restrict__ bo,
                 const float* __restrict__ pa, float* __restrict__ out) {
  __shared__ __align__(16) float U[512 * RBC];   // 16384 B
  __shared__ __align__(16) float h2[128 * RBC];  //  4096 B
  __shared__ float ssq[RBC];
  __shared__ float scal[RBC];
  __shared__ float red[256];

  const int t = threadIdx.x;
  const int R = blockIdx.x * RBC;
  if (t < RBC) ssq[t] = 0.f;
  __syncthreads();
  for (int i = t; i < 768; i += 256) {   // 8 rows x 96 float4
    int r = i / 96, q = i - r * 96;
    int col = q * 4;
    const float* src;
    int c2;
    if (col < 128)      { src = g1; c2 = col; }
    else if (col < 256) { src = g2; c2 = col - 128; }
    else                { src = cc; c2 = col - 256; }
    float4 v = *(const float4*)(src + (size_t)(R + r) * GOC + c2);
    U[(col + 0) * RBC + r] = v.x; U[(col + 1) * RBC + r] = v.y;
    U[(col + 2) * RBC + r] = v.z; U[(col + 3) * RBC + r] = v.w;
    atomicAdd(&ssq[r], v.x * v.x + v.y * v.y + v.z * v.z + v.w * v.w);
  }
  __syncthreads();
  if (t < RBC) scal[t] = 1.0f / fmaxf(sqrtf(ssq[t]), 1e-12f);
  __syncthreads();

  const float a = pa[0];
  const int r0 = (t & 1) * 4;
  const int f = t >> 1;

  float acc[4][4];
#pragma unroll
  for (int i = 0; i < 4; ++i)
#pragma unroll
    for (int j = 0; j < 4; ++j) acc[i][j] = 0.f;
#pragma unroll 2
  for (int k = 0; k < 384; ++k) {
    float4 h = *(const float4*)(U + k * RBC + r0);
    const float* wr = Wf1 + (size_t)k * 512 + f;
#pragma unroll
    for (int j = 0; j < 4; ++j) {
      float w = wr[j * 128];
      acc[0][j] = fmaf(h.x, w, acc[0][j]);
      acc[1][j] = fmaf(h.y, w, acc[1][j]);
      acc[2][j] = fmaf(h.z, w, acc[2][j]);
      acc[3][j] = fmaf(h.w, w, acc[3][j]);
    }
  }
  __syncthreads();   // xct dead -> U becomes h1
#pragma unroll
  for (int j = 0; j < 4; ++j) {
    int ff = f + j * 128;
    float bb = bf1[ff];
    float4 o;
    float v0 = acc[0][j] * scal[r0 + 0] + bb; o.x = v0 >= 0.f ? v0 : a * v0;
    float v1 = acc[1][j] * scal[r0 + 1] + bb; o.y = v1 >= 0.f ? v1 : a * v1;
    float v2 = acc[2][j] * scal[r0 + 2] + bb; o.z = v2 >= 0.f ? v2 : a * v2;
    float v3 = acc[3][j] * scal[r0 + 3] + bb; o.w = v3 >= 0.f ? v3 : a * v3;
    *(float4*)(U + ff * RBC + r0) = o;
  }
  __syncthreads();

  float a2[4] = {0.f, 0.f, 0.f, 0.f};
#pragma unroll 2
  for (int k = 0; k < 512; ++k) {
    float4 h = *(const float4*)(U + k * RBC + r0);
    float w = Wf2[(size_t)k * 128 + f];
    a2[0] = fmaf(h.x, w, a2[0]); a2[1] = fmaf(h.y, w, a2[1]);
    a2[2] = fmaf(h.z, w, a2[2]); a2[3] = fmaf(h.w, w, a2[3]);
  }
  {
    float bb = bf2[f];
#pragma unroll
    for (int i = 0; i < 4; ++i) {
      float v = a2[i] + bb;
      v = v >= 0.f ? v : a * v;
      h2[f * RBC + (r0 + i)] = v;   // h2 disjoint from U
    }
  }
  __syncthreads();

  {
    int rr = t >> 5, kp = t & 31;
    float p = 0.f;
#pragma unroll
    for (int jj = 0; jj < 4; ++jj) {
      int k = kp + 32 * jj;
      p = fmaf(h2[k * RBC + rr], Wo[k], p);
    }
    red[t] = p;
  }
  __syncthreads();
  if (t < RBC) {
    float ssum = bo[0];
#pragma unroll
    for (int i = 0; i < 32; ++i) ssum += red[t * 32 + i];
    out[R + t] = 1.0f / (1.0f + expf(-ssum));
  }
}

// ---------------------------------------------------------------------------
extern "C" void kernel_launch(void* const* d_in, const int* in_sizes, int n_in,
                              void* d_out, int out_size, void* d_ws, size_t ws_size,
                              hipStream_t stream) {
  const float* x1  = (const float*)d_in[0];
  const int*   ei1 = (const int*)d_in[1];
  const float* x2  = (const float*)d_in[2];
  const int*   ei2 = (const int*)d_in[3];
  const float* cel = (const float*)d_in[4];
  const float* W1  = (const float*)d_in[7];
  const float* b1  = (const float*)d_in[8];
  const float* W2  = (const float*)d_in[9];
  const float* b2  = (const float*)d_in[10];
  const float* W3  = (const float*)d_in[11];
  const float* b3  = (const float*)d_in[12];
  const float* Wg1 = (const float*)d_in[13];
  const float* bg1 = (const float*)d_in[14];
  const float* Wg2 = (const float*)d_in[15];
  const float* bg2 = (const float*)d_in[16];
  const float* Wr1 = (const float*)d_in[17];
  const float* br1 = (const float*)d_in[18];
  const float* Wr2 = (const float*)d_in[19];
  const float* br2 = (const float*)d_in[20];
  const float* Wr3 = (const float*)d_in[21];
  const float* br3 = (const float*)d_in[22];
  const float* Wf1 = (const float*)d_in[23];
  const float* bf1 = (const float*)d_in[24];
  const float* Wf2 = (const float*)d_in[25];
  const float* bf2 = (const float*)d_in[26];
  const float* Wo  = (const float*)d_in[27];
  const float* bo  = (const float*)d_in[28];
  const float* pa  = (const float*)d_in[29];

  float* ws    = (float*)d_ws;
  float* g1buf = ws;
  float* g2buf = ws + (size_t)N_GRAPHSC * GOC;
  float* cbuf  = ws + (size_t)2 * N_GRAPHSC * GOC;
  float* outp  = (float*)d_out;

  dim3 dgrid(N_GRAPHSC, 2);
  drug_kernel<<<dgrid, dim3(256), 0, stream>>>(
      x1, ei1, x2, ei2, W1, b1, W2, b2, W3, b3, Wg1, bg1, Wg2, bg2, g1buf);
  cell_kernel<<<dim3(N_GRAPHSC / RBC), dim3(256), 0, stream>>>(
      cel, Wr1, br1, Wr2, br2, Wr3, br3, cbuf);
  head_kernel<<<dim3(N_GRAPHSC / RBC), dim3(256), 0, stream>>>(
      g1buf, g2buf, cbuf, Wf1, bf1, Wf2, bf2, Wo, bo, pa, outp);
}

// Round 3
// 2223.034 us; speedup vs baseline: 1.4430x; 1.2887x over previous
//
#include <hip/hip_runtime.h>
#include <math.h>

#define N_EDGESC  1048576
#define N_GRAPHSC 8192
#define NPG 32     // nodes per graph
#define EPG 128    // edges per graph
#define FXD 78
#define F2C 156
#define F3C 312
#define GHC 156    // Wg1 out
#define GOC 128    // Wg2 out
#define HS  36     // padded node-stride
#define RBK 16     // rows per block in MLP kernels

// ---------------------------------------------------------------------------
// IN-PLACE multi-row A-aggregation: H[k][r] <- sum_c H[k][c] * A[r][c].
// Group g (8 lanes, cols r0..r0+3) owns rows k = g+32j, j<ROWS. The 4 As
// float4 loads per c-step are shared across all ROWS rows (key LDS saving).
// All loads precede all stores in the instruction stream -> in-place safe.
template<int FIN, int ROWS>
__device__ __forceinline__ void a_mult_ip(float* __restrict__ H,
                                          const float* __restrict__ As, int t) {
  const int r0 = (t & 7) * 4;
  const int g = t >> 3;
  float acc[ROWS][4];
  float* rowp[ROWS];
  bool valid[ROWS];
#pragma unroll
  for (int j = 0; j < ROWS; ++j) {
    int k = g + 32 * j;
    valid[j] = (k < FIN);
    rowp[j] = H + k * HS;
    acc[j][0] = acc[j][1] = acc[j][2] = acc[j][3] = 0.f;
  }
#pragma unroll
  for (int c = 0; c < NPG; c += 4) {
    float4 a0 = *(const float4*)(As + (c + 0) * HS + r0);
    float4 a1 = *(const float4*)(As + (c + 1) * HS + r0);
    float4 a2 = *(const float4*)(As + (c + 2) * HS + r0);
    float4 a3 = *(const float4*)(As + (c + 3) * HS + r0);
#pragma unroll
    for (int j = 0; j < ROWS; ++j) {
      if (valid[j]) {
        float4 h4 = *(const float4*)(rowp[j] + c);
        acc[j][0] = fmaf(h4.x, a0.x, acc[j][0]); acc[j][1] = fmaf(h4.x, a0.y, acc[j][1]);
        acc[j][2] = fmaf(h4.x, a0.z, acc[j][2]); acc[j][3] = fmaf(h4.x, a0.w, acc[j][3]);
        acc[j][0] = fmaf(h4.y, a1.x, acc[j][0]); acc[j][1] = fmaf(h4.y, a1.y, acc[j][1]);
        acc[j][2] = fmaf(h4.y, a1.z, acc[j][2]); acc[j][3] = fmaf(h4.y, a1.w, acc[j][3]);
        acc[j][0] = fmaf(h4.z, a2.x, acc[j][0]); acc[j][1] = fmaf(h4.z, a2.y, acc[j][1]);
        acc[j][2] = fmaf(h4.z, a2.z, acc[j][2]); acc[j][3] = fmaf(h4.z, a2.w, acc[j][3]);
        acc[j][0] = fmaf(h4.w, a3.x, acc[j][0]); acc[j][1] = fmaf(h4.w, a3.y, acc[j][1]);
        acc[j][2] = fmaf(h4.w, a3.z, acc[j][2]); acc[j][3] = fmaf(h4.w, a3.w, acc[j][3]);
      }
    }
  }
#pragma unroll
  for (int j = 0; j < ROWS; ++j) {
    if (valid[j]) {
      float4 o = {acc[j][0], acc[j][1], acc[j][2], acc[j][3]};
      *(float4*)(rowp[j] + r0) = o;
    }
  }
}

// Hout[f][n] = act( sum_k AH[k][n] * W[k][f] + b[f] ). Wide VEC so each
// ds_read_b128 feeds VEC*4 FMAs (LDS-unit is the drug bottleneck).
template<int FIN, int FOUT, int VEC, bool RELU, bool POOL>
__device__ __forceinline__ void mm_layer(const float* __restrict__ AH,
                                         const float* __restrict__ W,
                                         const float* __restrict__ bias,
                                         float* __restrict__ Hout,
                                         unsigned* __restrict__ gmax, int t) {
  const int n0 = (t & 7) * 4;
  constexpr int NF = FOUT / VEC;
  for (int fb = t >> 3; fb < NF; fb += 32) {
    const int f0 = fb * VEC;
    float acc[VEC][4];
#pragma unroll
    for (int v = 0; v < VEC; ++v) {
#pragma unroll
      for (int i = 0; i < 4; ++i) acc[v][i] = 0.f;
    }
#pragma unroll 2
    for (int k = 0; k < FIN; ++k) {
      float4 h = *(const float4*)(AH + k * HS + n0);
      const float* wp = W + (size_t)k * FOUT + f0;
      float wv[VEC];
      if constexpr (VEC == 8) {
        float4 wa = *(const float4*)wp; float4 wb = *(const float4*)(wp + 4);
        wv[0] = wa.x; wv[1] = wa.y; wv[2] = wa.z; wv[3] = wa.w;
        wv[4] = wb.x; wv[5] = wb.y; wv[6] = wb.z; wv[7] = wb.w;
      } else if constexpr (VEC == 6) {
        float2 wa = *(const float2*)wp; float2 wb = *(const float2*)(wp + 2);
        float2 wc = *(const float2*)(wp + 4);
        wv[0] = wa.x; wv[1] = wa.y; wv[2] = wb.x;
        wv[3] = wb.y; wv[4] = wc.x; wv[5] = wc.y;
      } else if constexpr (VEC == 4) {
        float4 wa = *(const float4*)wp;
        wv[0] = wa.x; wv[1] = wa.y; wv[2] = wa.z; wv[3] = wa.w;
      } else {
        float2 wa = *(const float2*)wp;
        wv[0] = wa.x; wv[1] = wa.y;
      }
#pragma unroll
      for (int v = 0; v < VEC; ++v) {
        acc[v][0] = fmaf(h.x, wv[v], acc[v][0]);
        acc[v][1] = fmaf(h.y, wv[v], acc[v][1]);
        acc[v][2] = fmaf(h.z, wv[v], acc[v][2]);
        acc[v][3] = fmaf(h.w, wv[v], acc[v][3]);
      }
    }
#pragma unroll
    for (int v = 0; v < VEC; ++v) {
      float bb = bias[f0 + v];
      float o0 = acc[v][0] + bb, o1 = acc[v][1] + bb;
      float o2 = acc[v][2] + bb, o3 = acc[v][3] + bb;
      if (RELU) {
        o0 = fmaxf(o0, 0.f); o1 = fmaxf(o1, 0.f);
        o2 = fmaxf(o2, 0.f); o3 = fmaxf(o3, 0.f);
      }
      if constexpr (POOL) {
        float m = fmaxf(fmaxf(o0, o1), fmaxf(o2, o3));
        atomicMax(&gmax[f0 + v], __float_as_uint(m));  // relu'd >= 0 -> monotone
      } else {
        float4 o = {o0, o1, o2, o3};
        *(float4*)(Hout + (f0 + v) * HS + n0) = o;
      }
    }
  }
}

// ---------------------------------------------------------------------------
// One block per graph, blockIdx.y = drug. LDS 38400 B -> 4 blocks/CU.
__global__ __launch_bounds__(256, 4)
void drug_kernel(const float* __restrict__ x1, const int* __restrict__ ei1,
                 const float* __restrict__ x2, const int* __restrict__ ei2,
                 const float* __restrict__ W1, const float* __restrict__ b1,
                 const float* __restrict__ W2, const float* __restrict__ b2,
                 const float* __restrict__ W3, const float* __restrict__ b3,
                 const float* __restrict__ Wg1, const float* __restrict__ bg1,
                 const float* __restrict__ Wg2, const float* __restrict__ bg2,
                 float* __restrict__ gout) {
  __shared__ __align__(16) float X[F2C * HS];   // 22464 B
  __shared__ __align__(16) float Y[FXD * HS];   // 11232 B
  __shared__ __align__(16) float As[NPG * HS];  //  4608 B
  // aliases into Y (lifetimes disjoint):
  float* deg = Y;
  float* gbuf = Y;
  unsigned* gbufU = (unsigned*)Y;
  float* gg = Y + 512;

  const int t = threadIdx.x;
  const int gid = blockIdx.x;
  const int drug = blockIdx.y;
  const float* __restrict__ x = drug ? x2 : x1;
  const int* __restrict__ ei = drug ? ei2 : ei1;
  const int nbase = gid * NPG;

  // ---- P0: zero deg + As, load x^T -> X
  if (t < NPG) deg[t] = 0.f;
  for (int i = t; i < NPG * HS; i += 256) As[i] = 0.f;
  const float* xg = x + (size_t)gid * (NPG * FXD);
  for (int i = t; i < (NPG * FXD) / 4; i += 256) {
    float4 v = ((const float4*)xg)[i];
    const float* vp = (const float*)&v;
    int idx = i * 4;
#pragma unroll
    for (int j = 0; j < 4; ++j) {
      int id2 = idx + j;
      int n = id2 / FXD;
      int k = id2 - n * FXD;
      X[k * HS + n] = vp[j];
    }
  }
  int s = 0, d = 0;
  if (t < EPG) {
    s = ei[(size_t)gid * EPG + t] - nbase;
    d = ei[(size_t)N_EDGESC + (size_t)gid * EPG + t] - nbase;
  }
  __syncthreads();
  if (t < EPG) atomicAdd(&deg[s], 1.0f);
  __syncthreads();
  if (t < EPG) {
    float w = rsqrtf(deg[s] + 1.0f) * rsqrtf(deg[d] + 1.0f);
    atomicAdd(&As[d * HS + s], w);   // A[s][d]: msg d->s
  }
  if (t < NPG) atomicAdd(&As[t * HS + t], 1.0f / (deg[t] + 1.0f));
  __syncthreads();

  // ---- layer 1
  a_mult_ip<FXD, 3>(X, As, t);
  __syncthreads();
  mm_layer<FXD, FXD, 6, true, false>(X, W1, b1, Y, nullptr, t);  // deg dead
  __syncthreads();
  // ---- layer 2
  a_mult_ip<FXD, 3>(Y, As, t);
  __syncthreads();
  mm_layer<FXD, F2C, 4, true, false>(Y, W2, b2, X, nullptr, t);
  __syncthreads();
  // ---- layer 3 + pool (Y dead: gbuf lives there)
  a_mult_ip<F2C, 5>(X, As, t);
  for (int i = t; i < F3C; i += 256) gbufU[i] = 0u;
  __syncthreads();
  mm_layer<F2C, F3C, 8, true, true>(X, W3, b3, nullptr, gbufU, t);
  __syncthreads();

  // ---- graph MLP
  if (t < GHC) {
    float acc = 0.f;
#pragma unroll 2
    for (int k = 0; k < F3C; k += 4) {
      float4 gv = *(const float4*)(gbuf + k);
      acc = fmaf(gv.x, Wg1[(k + 0) * GHC + t], acc);
      acc = fmaf(gv.y, Wg1[(k + 1) * GHC + t], acc);
      acc = fmaf(gv.z, Wg1[(k + 2) * GHC + t], acc);
      acc = fmaf(gv.w, Wg1[(k + 3) * GHC + t], acc);
    }
    gg[t] = fmaxf(acc + bg1[t], 0.f);
  }
  __syncthreads();
  if (t < GOC) {
    float acc = 0.f;
#pragma unroll 2
    for (int k = 0; k < GHC; k += 4) {
      float4 gv = *(const float4*)(gg + k);
      acc = fmaf(gv.x, Wg2[(k + 0) * GOC + t], acc);
      acc = fmaf(gv.y, Wg2[(k + 1) * GOC + t], acc);
      acc = fmaf(gv.z, Wg2[(k + 2) * GOC + t], acc);
      acc = fmaf(gv.w, Wg2[(k + 3) * GOC + t], acc);
    }
    gout[((size_t)drug * N_GRAPHSC + gid) * GOC + t] = acc + bg2[t];
  }
}

// ---------------------------------------------------------------------------
// Cell MLP: 16 rows/block, microtile 4 rows x 8 feats (32 FMA per b128).
// U holds ct k-tile then h1. LDS 49.2 KB -> 3 blocks/CU cap (grid gives 2).
__global__ __launch_bounds__(256, 3)
void cell_kernel(const float* __restrict__ cell,
                 const float* __restrict__ Wr1, const float* __restrict__ br1,
                 const float* __restrict__ Wr2, const float* __restrict__ br2,
                 const float* __restrict__ Wr3, const float* __restrict__ br3,
                 float* __restrict__ cout) {
  __shared__ __align__(16) float U[512 * RBK];   // 32768 B
  __shared__ __align__(16) float h2[256 * RBK];  // 16384 B
  const int t = threadIdx.x;
  const int R = blockIdx.x * RBK;
  const int r0 = (t & 3) * 4;
  const int f = t >> 2;  // [0,64)

  float acc[4][8];
#pragma unroll
  for (int i = 0; i < 4; ++i)
#pragma unroll
    for (int j = 0; j < 8; ++j) acc[i][j] = 0.f;

  for (int k0 = 0; k0 < 1000; k0 += 200) {
    __syncthreads();
    for (int i = t; i < 800; i += 256) {       // 16 rows x 50 float4
      int r = i / 50, k4 = i - r * 50;
      float4 v = *(const float4*)(cell + (size_t)(R + r) * 1000 + k0 + k4 * 4);
      int kk = k4 * 4;
      U[(kk + 0) * RBK + r] = v.x; U[(kk + 1) * RBK + r] = v.y;
      U[(kk + 2) * RBK + r] = v.z; U[(kk + 3) * RBK + r] = v.w;
    }
    __syncthreads();
#pragma unroll 4
    for (int k = 0; k < 200; ++k) {
      float4 h = *(const float4*)(U + k * RBK + r0);
      const float* wr = Wr1 + (size_t)(k0 + k) * 512 + f;
#pragma unroll
      for (int j = 0; j < 8; ++j) {
        float w = wr[j * 64];
        acc[0][j] = fmaf(h.x, w, acc[0][j]);
        acc[1][j] = fmaf(h.y, w, acc[1][j]);
        acc[2][j] = fmaf(h.z, w, acc[2][j]);
        acc[3][j] = fmaf(h.w, w, acc[3][j]);
      }
    }
  }
  __syncthreads();   // ct region dead -> U becomes h1
#pragma unroll
  for (int j = 0; j < 8; ++j) {
    int ff = f + j * 64;
    float bb = br1[ff];
    float4 o;
    o.x = fmaxf(acc[0][j] + bb, 0.f); o.y = fmaxf(acc[1][j] + bb, 0.f);
    o.z = fmaxf(acc[2][j] + bb, 0.f); o.w = fmaxf(acc[3][j] + bb, 0.f);
    *(float4*)(U + ff * RBK + r0) = o;
  }
  __syncthreads();

  float a2[4][4];
#pragma unroll
  for (int i = 0; i < 4; ++i)
#pragma unroll
    for (int j = 0; j < 4; ++j) a2[i][j] = 0.f;
#pragma unroll 4
  for (int k = 0; k < 512; ++k) {
    float4 h = *(const float4*)(U + k * RBK + r0);
    const float* wr = Wr2 + (size_t)k * 256 + f;
#pragma unroll
    for (int j = 0; j < 4; ++j) {
      float w = wr[j * 64];
      a2[0][j] = fmaf(h.x, w, a2[0][j]);
      a2[1][j] = fmaf(h.y, w, a2[1][j]);
      a2[2][j] = fmaf(h.z, w, a2[2][j]);
      a2[3][j] = fmaf(h.w, w, a2[3][j]);
    }
  }
#pragma unroll
  for (int j = 0; j < 4; ++j) {   // h2 disjoint from U: no barrier needed
    int ff = f + j * 64;
    float bb = br2[ff];
    float4 o;
    o.x = fmaxf(a2[0][j] + bb, 0.f); o.y = fmaxf(a2[1][j] + bb, 0.f);
    o.z = fmaxf(a2[2][j] + bb, 0.f); o.w = fmaxf(a2[3][j] + bb, 0.f);
    *(float4*)(h2 + ff * RBK + r0) = o;
  }
  __syncthreads();

  float a3[4][2];
#pragma unroll
  for (int i = 0; i < 4; ++i) { a3[i][0] = 0.f; a3[i][1] = 0.f; }
#pragma unroll 4
  for (int k = 0; k < 256; ++k) {
    float4 h = *(const float4*)(h2 + k * RBK + r0);
    const float* wr = Wr3 + (size_t)k * 128 + f;
#pragma unroll
    for (int j = 0; j < 2; ++j) {
      float w = wr[j * 64];
      a3[0][j] = fmaf(h.x, w, a3[0][j]);
      a3[1][j] = fmaf(h.y, w, a3[1][j]);
      a3[2][j] = fmaf(h.z, w, a3[2][j]);
      a3[3][j] = fmaf(h.w, w, a3[3][j]);
    }
  }
#pragma unroll
  for (int j = 0; j < 2; ++j) {
    int ff = f + j * 64;
    float bb = br3[ff];
#pragma unroll
    for (int i = 0; i < 4; ++i)
      cout[(size_t)(R + r0 + i) * GOC + ff] = a3[i][j] + bb;  // no relu
  }
}

// ---------------------------------------------------------------------------
// Head: 16 rows/block. U holds xct then h1; h2 separate. ~41.2 KB.
__global__ __launch_bounds__(256, 3)
void head_kernel(const float* __restrict__ g1, const float* __restrict__ g2,
                 const float* __restrict__ cc,
                 const float* __restrict__ Wf1, const float* __restrict__ bf1,
                 const float* __restrict__ Wf2, const float* __restrict__ bf2,
                 const float* __restrict__ Wo, const float* __restrict__ bo,
                 const float* __restrict__ pa, float* __restrict__ out) {
  __shared__ __align__(16) float U[512 * RBK];   // 32768 B
  __shared__ __align__(16) float h2[128 * RBK];  //  8192 B
  __shared__ float ssq[RBK];
  __shared__ float scal[RBK];
  __shared__ float red[256];

  const int t = threadIdx.x;
  const int R = blockIdx.x * RBK;
  if (t < RBK) ssq[t] = 0.f;
  __syncthreads();
  for (int i = t; i < 1536; i += 256) {   // 16 rows x 96 float4
    int r = i / 96, q = i - r * 96;
    int col = q * 4;
    const float* src;
    int c2;
    if (col < 128)      { src = g1; c2 = col; }
    else if (col < 256) { src = g2; c2 = col - 128; }
    else                { src = cc; c2 = col - 256; }
    float4 v = *(const float4*)(src + (size_t)(R + r) * GOC + c2);
    U[(col + 0) * RBK + r] = v.x; U[(col + 1) * RBK + r] = v.y;
    U[(col + 2) * RBK + r] = v.z; U[(col + 3) * RBK + r] = v.w;
    atomicAdd(&ssq[r], v.x * v.x + v.y * v.y + v.z * v.z + v.w * v.w);
  }
  __syncthreads();
  if (t < RBK) scal[t] = 1.0f / fmaxf(sqrtf(ssq[t]), 1e-12f);
  __syncthreads();

  const float a = pa[0];
  const int r0 = (t & 3) * 4;
  const int f = t >> 2;  // [0,64)

  float acc[4][8];
#pragma unroll
  for (int i = 0; i < 4; ++i)
#pragma unroll
    for (int j = 0; j < 8; ++j) acc[i][j] = 0.f;
#pragma unroll 4
  for (int k = 0; k < 384; ++k) {
    float4 h = *(const float4*)(U + k * RBK + r0);
    const float* wr = Wf1 + (size_t)k * 512 + f;
#pragma unroll
    for (int j = 0; j < 8; ++j) {
      float w = wr[j * 64];
      acc[0][j] = fmaf(h.x, w, acc[0][j]);
      acc[1][j] = fmaf(h.y, w, acc[1][j]);
      acc[2][j] = fmaf(h.z, w, acc[2][j]);
      acc[3][j] = fmaf(h.w, w, acc[3][j]);
    }
  }
  __syncthreads();   // xct dead -> U becomes h1
#pragma unroll
  for (int j = 0; j < 8; ++j) {
    int ff = f + j * 64;
    float bb = bf1[ff];
    float4 o;
    float v0 = acc[0][j] * scal[r0 + 0] + bb; o.x = v0 >= 0.f ? v0 : a * v0;
    float v1 = acc[1][j] * scal[r0 + 1] + bb; o.y = v1 >= 0.f ? v1 : a * v1;
    float v2 = acc[2][j] * scal[r0 + 2] + bb; o.z = v2 >= 0.f ? v2 : a * v2;
    float v3 = acc[3][j] * scal[r0 + 3] + bb; o.w = v3 >= 0.f ? v3 : a * v3;
    *(float4*)(U + ff * RBK + r0) = o;
  }
  __syncthreads();

  float a2[4][2];
#pragma unroll
  for (int i = 0; i < 4; ++i) { a2[i][0] = 0.f; a2[i][1] = 0.f; }
#pragma unroll 4
  for (int k = 0; k < 512; ++k) {
    float4 h = *(const float4*)(U + k * RBK + r0);
    const float* wr = Wf2 + (size_t)k * 128 + f;
#pragma unroll
    for (int j = 0; j < 2; ++j) {
      float w = wr[j * 64];
      a2[0][j] = fmaf(h.x, w, a2[0][j]);
      a2[1][j] = fmaf(h.y, w, a2[1][j]);
      a2[2][j] = fmaf(h.z, w, a2[2][j]);
      a2[3][j] = fmaf(h.w, w, a2[3][j]);
    }
  }
  {
#pragma unroll
    for (int j = 0; j < 2; ++j) {   // h2 disjoint from U
      int ff = f + j * 64;
      float bb = bf2[ff];
#pragma unroll
      for (int i = 0; i < 4; ++i) {
        float v = a2[i][j] + bb;
        v = v >= 0.f ? v : a * v;
        h2[ff * RBK + (r0 + i)] = v;
      }
    }
  }
  __syncthreads();

  {
    int rr = t >> 4, kp = t & 15;
    float p = 0.f;
#pragma unroll
    for (int jj = 0; jj < 8; ++jj) {
      int k = kp + 16 * jj;
      p = fmaf(h2[k * RBK + rr], Wo[k], p);
    }
    red[t] = p;
  }
  __syncthreads();
  if (t < RBK) {
    float ssum = bo[0];
#pragma unroll
    for (int i = 0; i < 16; ++i) ssum += red[t * 16 + i];
    out[R + t] = 1.0f / (1.0f + expf(-ssum));
  }
}

// ---------------------------------------------------------------------------
extern "C" void kernel_launch(void* const* d_in, const int* in_sizes, int n_in,
                              void* d_out, int out_size, void* d_ws, size_t ws_size,
                              hipStream_t stream) {
  const float* x1  = (const float*)d_in[0];
  const int*   ei1 = (const int*)d_in[1];
  const float* x2  = (const float*)d_in[2];
  const int*   ei2 = (const int*)d_in[3];
  const float* cel = (const float*)d_in[4];
  const float* W1  = (const float*)d_in[7];
  const float* b1  = (const float*)d_in[8];
  const float* W2  = (const float*)d_in[9];
  const float* b2  = (const float*)d_in[10];
  const float* W3  = (const float*)d_in[11];
  const float* b3  = (const float*)d_in[12];
  const float* Wg1 = (const float*)d_in[13];
  const float* bg1 = (const float*)d_in[14];
  const float* Wg2 = (const float*)d_in[15];
  const float* bg2 = (const float*)d_in[16];
  const float* Wr1 = (const float*)d_in[17];
  const float* br1 = (const float*)d_in[18];
  const float* Wr2 = (const float*)d_in[19];
  const float* br2 = (const float*)d_in[20];
  const float* Wr3 = (const float*)d_in[21];
  const float* br3 = (const float*)d_in[22];
  const float* Wf1 = (const float*)d_in[23];
  const float* bf1 = (const float*)d_in[24];
  const float* Wf2 = (const float*)d_in[25];
  const float* bf2 = (const float*)d_in[26];
  const float* Wo  = (const float*)d_in[27];
  const float* bo  = (const float*)d_in[28];
  const float* pa  = (const float*)d_in[29];

  float* ws    = (float*)d_ws;
  float* g1buf = ws;
  float* g2buf = ws + (size_t)N_GRAPHSC * GOC;
  float* cbuf  = ws + (size_t)2 * N_GRAPHSC * GOC;
  float* outp  = (float*)d_out;

  dim3 dgrid(N_GRAPHSC, 2);
  drug_kernel<<<dgrid, dim3(256), 0, stream>>>(
      x1, ei1, x2, ei2, W1, b1, W2, b2, W3, b3, Wg1, bg1, Wg2, bg2, g1buf);
  cell_kernel<<<dim3(N_GRAPHSC / RBK), dim3(256), 0, stream>>>(
      cel, Wr1, br1, Wr2, br2, Wr3, br3, cbuf);
  head_kernel<<<dim3(N_GRAPHSC / RBK), dim3(256), 0, stream>>>(
      g1buf, g2buf, cbuf, Wf1, bf1, Wf2, bf2, Wo, bo, pa, outp);
}